// Round 1
// baseline (488.914 us; speedup 1.0000x reference)
//
#include <hip/hip_runtime.h>
#include <hip/hip_bf16.h>

typedef __attribute__((ext_vector_type(8))) short short8;
typedef __attribute__((ext_vector_type(4))) short s16x4;
typedef __attribute__((ext_vector_type(4))) float f32x4;

#define DIMV 512
#define NHEAD 8
#define HD 64
#define NBATCH 8
#define NQL 1024
#define NKL 1024

__device__ __forceinline__ short f2bf(float f) {
    unsigned int u = __float_as_uint(f);
    unsigned int r = (u + 0x7fffu + ((u >> 16) & 1u)) >> 16;
    return (short)r;
}

// ---------------- f32 -> bf16 convert ----------------
__global__ void k_f32_to_bf16(const float* __restrict__ in, short* __restrict__ out, int n) {
    int i = (blockIdx.x * blockDim.x + threadIdx.x) * 4;
    if (i < n) {
        float4 v = *reinterpret_cast<const float4*>(in + i);
        s16x4 o;
        o[0] = f2bf(v.x); o[1] = f2bf(v.y); o[2] = f2bf(v.z); o[3] = f2bf(v.w);
        *reinterpret_cast<s16x4*>(out + i) = o;
    }
}

// ---------------- W[k][n] f32 -> Wt[n][k] bf16 ----------------
__global__ void k_transpose_w(const float* __restrict__ W, short* __restrict__ Wt) {
    __shared__ float tile[32][33];
    int tx = threadIdx.x, ty = threadIdx.y;           // 32 x 8
    int n0 = blockIdx.x * 32, k0 = blockIdx.y * 32;
    for (int r = 0; r < 4; ++r)
        tile[ty + r * 8][tx] = W[(size_t)(k0 + ty + r * 8) * DIMV + n0 + tx];
    __syncthreads();
    for (int r = 0; r < 4; ++r)
        Wt[(size_t)(n0 + ty + r * 8) * DIMV + k0 + tx] = f2bf(tile[tx][ty + r * 8]);
}

// ---------------- GEMM: C[M,512] = A[M,512] @ W  (Bt = W^T, [n][k]) ----------------
// mode 0: outF = acc+bias (f32) and outB = bf16(acc+bias)
// mode 1: outB = bf16(acc+bias)
// mode 2: outF = resid + relu(acc+bias)
#define GLS 40  // LDS k-stride (32 + 8 pad)
__global__ __launch_bounds__(256) void k_gemm(
    const short* __restrict__ A, const short* __restrict__ Bt,
    const float* __restrict__ bias,
    float* __restrict__ outF, short* __restrict__ outB,
    const float* __restrict__ resid, int mode)
{
    __shared__ __align__(16) short As[128 * GLS];
    __shared__ __align__(16) short Bs[128 * GLS];
    int tid = threadIdx.x;
    int lane = tid & 63, wid = tid >> 6;
    int wr = wid >> 1, wc = wid & 1;
    int c = lane & 15, g = lane >> 4;
    int m0 = blockIdx.y * 128, n0 = blockIdx.x * 128;

    f32x4 acc[4][4] = {};

    for (int k0 = 0; k0 < 512; k0 += 32) {
        for (int p = 0; p < 2; ++p) {
            int idx = p * 256 + tid;
            int r = idx >> 2, kc = (idx & 3) * 8;
            *reinterpret_cast<short8*>(&As[r * GLS + kc]) =
                *reinterpret_cast<const short8*>(&A[(size_t)(m0 + r) * 512 + k0 + kc]);
            *reinterpret_cast<short8*>(&Bs[r * GLS + kc]) =
                *reinterpret_cast<const short8*>(&Bt[(size_t)(n0 + r) * 512 + k0 + kc]);
        }
        __syncthreads();
        short8 af[4], bfr[4];
        for (int i = 0; i < 4; ++i)
            af[i] = *reinterpret_cast<short8*>(&As[(wr * 64 + i * 16 + c) * GLS + g * 8]);
        for (int j = 0; j < 4; ++j)
            bfr[j] = *reinterpret_cast<short8*>(&Bs[(wc * 64 + j * 16 + c) * GLS + g * 8]);
        for (int i = 0; i < 4; ++i)
            for (int j = 0; j < 4; ++j)
                acc[i][j] = __builtin_amdgcn_mfma_f32_16x16x32_bf16(af[i], bfr[j], acc[i][j], 0, 0, 0);
        __syncthreads();
    }

    for (int i = 0; i < 4; ++i)
        for (int j = 0; j < 4; ++j) {
            int row = m0 + wr * 64 + i * 16 + g * 4;
            int col = n0 + wc * 64 + j * 16 + c;
            float bb = bias[col];
            for (int q = 0; q < 4; ++q) {
                size_t idx = (size_t)(row + q) * 512 + col;
                float v = acc[i][j][q] + bb;
                if (mode == 0)      { outF[idx] = v; outB[idx] = f2bf(v); }
                else if (mode == 1) { outB[idx] = f2bf(v); }
                else                { outF[idx] = resid[idx] + fmaxf(v, 0.f); }
            }
        }
}

// ---------------- fused flash attention with residual ----------------
__global__ __launch_bounds__(256) void k_attn(
    const short* __restrict__ Qb, const short* __restrict__ Kb,
    const short* __restrict__ Vb, const float* __restrict__ Resid,
    float* __restrict__ Out)
{
    __shared__ __align__(16) short Qs[64 * 72];
    __shared__ __align__(16) short Ks[64 * 72];
    __shared__ __align__(16) short Vt[64 * 72];
    __shared__ __align__(16) short Ps[64 * 72];
    int tid = threadIdx.x;
    int lane = tid & 63, w = tid >> 6;
    int c = lane & 15, g = lane >> 4;
    int bid = blockIdx.x;
    int qb = bid & 15, h = (bid >> 4) & 7, b = bid >> 7;
    const short* Qg = Qb + (size_t)(b * NQL + qb * 64) * 512 + h * 64;
    const short* Kg = Kb + (size_t)b * NKL * 512 + h * 64;
    const short* Vg = Vb + (size_t)b * NKL * 512 + h * 64;
    const float* Rg = Resid + (size_t)(b * NQL + qb * 64) * 512 + h * 64;
    float* Og = Out + (size_t)(b * NQL + qb * 64) * 512 + h * 64;

    for (int p = 0; p < 2; ++p) {
        int idx = p * 256 + tid;
        int r = idx >> 3, d0 = (idx & 7) * 8;
        *reinterpret_cast<short8*>(&Qs[r * 72 + d0]) =
            *reinterpret_cast<const short8*>(&Qg[(size_t)r * 512 + d0]);
    }
    float m = -1e30f, l = 0.f;
    f32x4 o[4] = {};
    const float scale = 0.04419417382415922f;  // 1/sqrt(512)

    for (int k0 = 0; k0 < NKL; k0 += 64) {
        for (int p = 0; p < 2; ++p) {
            int idx = p * 256 + tid;
            int r = idx >> 3, d0 = (idx & 7) * 8;
            *reinterpret_cast<short8*>(&Ks[r * 72 + d0]) =
                *reinterpret_cast<const short8*>(&Kg[(size_t)(k0 + r) * 512 + d0]);
        }
        {
            int kv = tid & 63;
            for (int p = 0; p < 2; ++p) {
                int d0 = ((tid >> 6) + p * 4) * 8;
                short8 v = *reinterpret_cast<const short8*>(&Vg[(size_t)(k0 + kv) * 512 + d0]);
                for (int j = 0; j < 8; ++j) Vt[(d0 + j) * 72 + kv] = v[j];
            }
        }
        __syncthreads();

        // S^T = K * Q^T : per wave kv(4 frags) x 16 q-cols
        f32x4 s[4] = {};
        for (int ks = 0; ks < 2; ++ks) {
            short8 bq = *reinterpret_cast<short8*>(&Qs[(w * 16 + c) * 72 + ks * 32 + g * 8]);
            for (int i = 0; i < 4; ++i) {
                short8 ak = *reinterpret_cast<short8*>(&Ks[(i * 16 + c) * 72 + ks * 32 + g * 8]);
                s[i] = __builtin_amdgcn_mfma_f32_16x16x32_bf16(ak, bq, s[i], 0, 0, 0);
            }
        }

        // online softmax; lane owns q = w*16+c, holds kv = i*16 + g*4 + reg
        float rowm = -1e30f;
        for (int i = 0; i < 4; ++i)
            for (int q = 0; q < 4; ++q)
                rowm = fmaxf(rowm, s[i][q]);
        rowm *= scale;
        rowm = fmaxf(rowm, __shfl_xor(rowm, 16));
        rowm = fmaxf(rowm, __shfl_xor(rowm, 32));
        float mnew = fmaxf(m, rowm);
        float corr = __expf(m - mnew);
        float psum = 0.f;
        for (int i = 0; i < 4; ++i)
            for (int q = 0; q < 4; ++q) {
                float p = __expf(s[i][q] * scale - mnew);
                psum += p;
                Ps[(w * 16 + c) * 72 + i * 16 + g * 4 + q] = f2bf(p);
            }
        psum += __shfl_xor(psum, 16);
        psum += __shfl_xor(psum, 32);
        l = l * corr + psum;
        m = mnew;
        float cq[4];
        for (int q = 0; q < 4; ++q) cq[q] = __shfl(corr, g * 4 + q);
        for (int jf = 0; jf < 4; ++jf)
            for (int q = 0; q < 4; ++q)
                o[jf][q] *= cq[q];

        // O += P * V   (P rows = q, Vt[d][kv])
        for (int ks = 0; ks < 2; ++ks) {
            short8 pa = *reinterpret_cast<short8*>(&Ps[(w * 16 + c) * 72 + ks * 32 + g * 8]);
            for (int jf = 0; jf < 4; ++jf) {
                short8 vb = *reinterpret_cast<short8*>(&Vt[(jf * 16 + c) * 72 + ks * 32 + g * 8]);
                o[jf] = __builtin_amdgcn_mfma_f32_16x16x32_bf16(pa, vb, o[jf], 0, 0, 0);
            }
        }
        __syncthreads();
    }

    float lq[4];
    for (int q = 0; q < 4; ++q) lq[q] = 1.f / __shfl(l, g * 4 + q);
    for (int jf = 0; jf < 4; ++jf)
        for (int q = 0; q < 4; ++q) {
            int r = w * 16 + g * 4 + q;
            int d = jf * 16 + c;
            size_t idx = (size_t)r * 512 + d;
            Og[idx] = o[jf][q] * lq[q] + Rg[idx];
        }
}

// ---------------- LayerNorm (one wave per 512-row) ----------------
__global__ __launch_bounds__(64) void k_ln(
    const float* __restrict__ in, float* __restrict__ outF,
    short* __restrict__ outB, const float* __restrict__ gamma,
    const float* __restrict__ beta)
{
    int row = blockIdx.x, lane = threadIdx.x;
    const float* x = in + (size_t)row * 512;
    float4 v0 = *reinterpret_cast<const float4*>(&x[lane * 8]);
    float4 v1 = *reinterpret_cast<const float4*>(&x[lane * 8 + 4]);
    float vals[8] = {v0.x, v0.y, v0.z, v0.w, v1.x, v1.y, v1.z, v1.w};
    float sum = 0.f, sq = 0.f;
    for (int j = 0; j < 8; ++j) { sum += vals[j]; sq += vals[j] * vals[j]; }
    for (int mask = 32; mask; mask >>= 1) {
        sum += __shfl_xor(sum, mask);
        sq  += __shfl_xor(sq, mask);
    }
    float mean = sum * (1.f / 512.f);
    float var  = sq * (1.f / 512.f) - mean * mean;
    float rstd = rsqrtf(var + 1e-5f);
    for (int j = 0; j < 8; ++j) {
        int col = lane * 8 + j;
        float y = (vals[j] - mean) * rstd * gamma[col] + beta[col];
        size_t idx = (size_t)row * 512 + col;
        if (outF) outF[idx] = y;
        if (outB) outB[idx] = f2bf(y);
    }
}

extern "C" void kernel_launch(void* const* d_in, const int* in_sizes, int n_in,
                              void* d_out, int out_size, void* d_ws, size_t ws_size,
                              hipStream_t stream) {
    const float* Q   = (const float*)d_in[0];
    const float* K   = (const float*)d_in[1];
    const float* Wq  = (const float*)d_in[2];
    const float* bq  = (const float*)d_in[3];
    const float* Wk  = (const float*)d_in[4];
    const float* bk  = (const float*)d_in[5];
    const float* Wv  = (const float*)d_in[6];
    const float* bv  = (const float*)d_in[7];
    const float* Wo  = (const float*)d_in[8];
    const float* bo  = (const float*)d_in[9];
    const float* g0  = (const float*)d_in[10];
    const float* be0 = (const float*)d_in[11];
    const float* g1  = (const float*)d_in[12];
    const float* be1 = (const float*)d_in[13];
    float* out = (float*)d_out;
    char* ws = (char*)d_ws;
    const size_t MB = 1024 * 1024;

    short* Qb   = (short*)(ws + 0);
    short* Kb   = (short*)(ws + 8 * MB);
    short* Wqt  = (short*)(ws + 16 * MB);
    short* Wkt  = (short*)(ws + 16 * MB + 512 * 1024);
    short* Wvt  = (short*)(ws + 17 * MB);
    short* Wot  = (short*)(ws + 17 * MB + 512 * 1024);
    float* Qp   = (float*)(ws + 18 * MB);
    short* Qpb  = (short*)(ws + 34 * MB);
    short* Kpb  = (short*)(ws + 42 * MB);
    short* Vpb  = (short*)(ws + 50 * MB);
    float* Oa   = (float*)(ws + 0);        // reuses Qb/Kb
    float* ln0f = (float*)(ws + 42 * MB);  // reuses Kpb/Vpb
    short* ln0b = (short*)(ws + 34 * MB);  // reuses Qpb
    float* out2 = (float*)(ws + 18 * MB);  // reuses Qp

    int n = NBATCH * NQL * DIMV;  // 4194304
    k_f32_to_bf16<<<n / 4 / 256, 256, 0, stream>>>(Q, Qb, n);
    k_f32_to_bf16<<<n / 4 / 256, 256, 0, stream>>>(K, Kb, n);
    dim3 tb(32, 8), tg(16, 16);
    k_transpose_w<<<tg, tb, 0, stream>>>(Wq, Wqt);
    k_transpose_w<<<tg, tb, 0, stream>>>(Wk, Wkt);
    k_transpose_w<<<tg, tb, 0, stream>>>(Wv, Wvt);
    k_transpose_w<<<tg, tb, 0, stream>>>(Wo, Wot);

    dim3 gg(4, 64);  // N/128 x M/128
    k_gemm<<<gg, 256, 0, stream>>>(Qb, Wqt, bq, Qp, Qpb, nullptr, 0);
    k_gemm<<<gg, 256, 0, stream>>>(Kb, Wkt, bk, nullptr, Kpb, nullptr, 1);
    k_gemm<<<gg, 256, 0, stream>>>(Kb, Wvt, bv, nullptr, Vpb, nullptr, 1);

    k_attn<<<NBATCH * NHEAD * (NQL / 64), 256, 0, stream>>>(Qpb, Kpb, Vpb, Qp, Oa);

    k_ln<<<NBATCH * NQL, 64, 0, stream>>>(Oa, ln0f, ln0b, g0, be0);
    k_gemm<<<gg, 256, 0, stream>>>(ln0b, Wot, bo, out2, nullptr, ln0f, 2);
    k_ln<<<NBATCH * NQL, 64, 0, stream>>>(out2, out, nullptr, g1, be1);
}

// Round 2
// 186.308 us; speedup vs baseline: 2.6242x; 2.6242x over previous
//
#include <hip/hip_runtime.h>
#include <hip/hip_bf16.h>

typedef __attribute__((ext_vector_type(8))) short short8;
typedef __attribute__((ext_vector_type(4))) short s16x4;
typedef __attribute__((ext_vector_type(4))) float f32x4;

#define DIMV 512
#define NHEAD 8
#define HD 64
#define NBATCH 8
#define NQL 1024
#define NKL 1024

__device__ __forceinline__ short f2bf(float f) {
    unsigned int u = __float_as_uint(f);
    unsigned int r = (u + 0x7fffu + ((u >> 16) & 1u)) >> 16;
    return (short)r;
}

// ---------------- f32 -> bf16 convert ----------------
__global__ void k_f32_to_bf16(const float* __restrict__ in, short* __restrict__ out, int n) {
    int i = (blockIdx.x * blockDim.x + threadIdx.x) * 4;
    if (i < n) {
        float4 v = *reinterpret_cast<const float4*>(in + i);
        s16x4 o;
        o[0] = f2bf(v.x); o[1] = f2bf(v.y); o[2] = f2bf(v.z); o[3] = f2bf(v.w);
        *reinterpret_cast<s16x4*>(out + i) = o;
    }
}

// ---------------- W[k][n] f32 -> Wt[n][k] bf16 ----------------
__global__ void k_transpose_w(const float* __restrict__ W, short* __restrict__ Wt) {
    __shared__ float tile[32][33];
    int tx = threadIdx.x, ty = threadIdx.y;           // 32 x 8
    int n0 = blockIdx.x * 32, k0 = blockIdx.y * 32;
    #pragma unroll
    for (int r = 0; r < 4; ++r)
        tile[ty + r * 8][tx] = W[(size_t)(k0 + ty + r * 8) * DIMV + n0 + tx];
    __syncthreads();
    #pragma unroll
    for (int r = 0; r < 4; ++r)
        Wt[(size_t)(n0 + ty + r * 8) * DIMV + k0 + tx] = f2bf(tile[tx][ty + r * 8]);
}

// ---------------- GEMM: C[M,512] = A[M,512] @ W  (Bt = W^T, [n][k]) ----------------
// MODE 0: outF = acc+bias (f32) and outB = bf16(acc+bias)
// MODE 1: outB = bf16(acc+bias)
// MODE 2: outF = resid + relu(acc+bias)
#define GLS 40  // LDS k-stride (32 + 8 pad)
template<int MODE>
__global__ __launch_bounds__(256) void k_gemm(
    const short* __restrict__ A, const short* __restrict__ Bt,
    const float* __restrict__ bias,
    float* __restrict__ outF, short* __restrict__ outB,
    const float* __restrict__ resid)
{
    __shared__ __align__(16) short As[128 * GLS];
    __shared__ __align__(16) short Bs[128 * GLS];
    int tid = threadIdx.x;
    int lane = tid & 63, wid = tid >> 6;
    int wr = wid >> 1, wc = wid & 1;
    int c = lane & 15, g = lane >> 4;
    int m0 = blockIdx.y * 128, n0 = blockIdx.x * 128;

    f32x4 acc[4][4] = {};

    for (int k0 = 0; k0 < 512; k0 += 32) {
        #pragma unroll
        for (int p = 0; p < 2; ++p) {
            int idx = p * 256 + tid;
            int r = idx >> 2, kc = (idx & 3) * 8;
            *reinterpret_cast<short8*>(&As[r * GLS + kc]) =
                *reinterpret_cast<const short8*>(&A[(size_t)(m0 + r) * 512 + k0 + kc]);
            *reinterpret_cast<short8*>(&Bs[r * GLS + kc]) =
                *reinterpret_cast<const short8*>(&Bt[(size_t)(n0 + r) * 512 + k0 + kc]);
        }
        __syncthreads();
        short8 af[4], bfr[4];
        #pragma unroll
        for (int i = 0; i < 4; ++i)
            af[i] = *reinterpret_cast<short8*>(&As[(wr * 64 + i * 16 + c) * GLS + g * 8]);
        #pragma unroll
        for (int j = 0; j < 4; ++j)
            bfr[j] = *reinterpret_cast<short8*>(&Bs[(wc * 64 + j * 16 + c) * GLS + g * 8]);
        #pragma unroll
        for (int i = 0; i < 4; ++i)
            #pragma unroll
            for (int j = 0; j < 4; ++j)
                acc[i][j] = __builtin_amdgcn_mfma_f32_16x16x32_bf16(af[i], bfr[j], acc[i][j], 0, 0, 0);
        __syncthreads();
    }

    #pragma unroll
    for (int i = 0; i < 4; ++i)
        #pragma unroll
        for (int j = 0; j < 4; ++j) {
            int row = m0 + wr * 64 + i * 16 + g * 4;
            int col = n0 + wc * 64 + j * 16 + c;
            float bb = bias[col];
            #pragma unroll
            for (int q = 0; q < 4; ++q) {
                size_t idx = (size_t)(row + q) * 512 + col;
                float v = acc[i][j][q] + bb;
                if (MODE == 0)      { outF[idx] = v; outB[idx] = f2bf(v); }
                else if (MODE == 1) { outB[idx] = f2bf(v); }
                else                { outF[idx] = resid[idx] + fmaxf(v, 0.f); }
            }
        }
}

// ---------------- fused flash attention with residual ----------------
__global__ __launch_bounds__(256) void k_attn(
    const short* __restrict__ Qb, const short* __restrict__ Kb,
    const short* __restrict__ Vb, const float* __restrict__ Resid,
    float* __restrict__ Out)
{
    __shared__ __align__(16) short Qs[64 * 72];
    __shared__ __align__(16) short Ks[64 * 72];
    __shared__ __align__(16) short Vt[64 * 72];
    __shared__ __align__(16) short Ps[64 * 72];
    int tid = threadIdx.x;
    int lane = tid & 63, w = tid >> 6;
    int c = lane & 15, g = lane >> 4;
    int bid = blockIdx.x;
    int qb = bid & 15, h = (bid >> 4) & 7, b = bid >> 7;
    const short* Qg = Qb + (size_t)(b * NQL + qb * 64) * 512 + h * 64;
    const short* Kg = Kb + (size_t)b * NKL * 512 + h * 64;
    const short* Vg = Vb + (size_t)b * NKL * 512 + h * 64;
    const float* Rg = Resid + (size_t)(b * NQL + qb * 64) * 512 + h * 64;
    float* Og = Out + (size_t)(b * NQL + qb * 64) * 512 + h * 64;

    #pragma unroll
    for (int p = 0; p < 2; ++p) {
        int idx = p * 256 + tid;
        int r = idx >> 3, d0 = (idx & 7) * 8;
        *reinterpret_cast<short8*>(&Qs[r * 72 + d0]) =
            *reinterpret_cast<const short8*>(&Qg[(size_t)r * 512 + d0]);
    }
    float m = -1e30f, l = 0.f;
    f32x4 o[4] = {};
    const float scale = 0.04419417382415922f;  // 1/sqrt(512)

    for (int k0 = 0; k0 < NKL; k0 += 64) {
        #pragma unroll
        for (int p = 0; p < 2; ++p) {
            int idx = p * 256 + tid;
            int r = idx >> 3, d0 = (idx & 7) * 8;
            *reinterpret_cast<short8*>(&Ks[r * 72 + d0]) =
                *reinterpret_cast<const short8*>(&Kg[(size_t)(k0 + r) * 512 + d0]);
        }
        {
            int kv = tid & 63;
            #pragma unroll
            for (int p = 0; p < 2; ++p) {
                int d0 = ((tid >> 6) + p * 4) * 8;
                short8 v = *reinterpret_cast<const short8*>(&Vg[(size_t)(k0 + kv) * 512 + d0]);
                #pragma unroll
                for (int j = 0; j < 8; ++j) Vt[(d0 + j) * 72 + kv] = v[j];
            }
        }
        __syncthreads();

        // S^T = K * Q^T : per wave kv(4 frags) x 16 q-cols
        f32x4 s[4] = {};
        #pragma unroll
        for (int ks = 0; ks < 2; ++ks) {
            short8 bq = *reinterpret_cast<short8*>(&Qs[(w * 16 + c) * 72 + ks * 32 + g * 8]);
            #pragma unroll
            for (int i = 0; i < 4; ++i) {
                short8 ak = *reinterpret_cast<short8*>(&Ks[(i * 16 + c) * 72 + ks * 32 + g * 8]);
                s[i] = __builtin_amdgcn_mfma_f32_16x16x32_bf16(ak, bq, s[i], 0, 0, 0);
            }
        }

        // online softmax; lane owns q = w*16+c, holds kv = i*16 + g*4 + reg
        float rowm = -1e30f;
        #pragma unroll
        for (int i = 0; i < 4; ++i)
            #pragma unroll
            for (int q = 0; q < 4; ++q)
                rowm = fmaxf(rowm, s[i][q]);
        rowm *= scale;
        rowm = fmaxf(rowm, __shfl_xor(rowm, 16));
        rowm = fmaxf(rowm, __shfl_xor(rowm, 32));
        float mnew = fmaxf(m, rowm);
        float corr = __expf(m - mnew);
        float psum = 0.f;
        #pragma unroll
        for (int i = 0; i < 4; ++i)
            #pragma unroll
            for (int q = 0; q < 4; ++q) {
                float p = __expf(s[i][q] * scale - mnew);
                psum += p;
                Ps[(w * 16 + c) * 72 + i * 16 + g * 4 + q] = f2bf(p);
            }
        psum += __shfl_xor(psum, 16);
        psum += __shfl_xor(psum, 32);
        l = l * corr + psum;
        m = mnew;
        float cq[4];
        #pragma unroll
        for (int q = 0; q < 4; ++q) cq[q] = __shfl(corr, g * 4 + q);
        #pragma unroll
        for (int jf = 0; jf < 4; ++jf)
            #pragma unroll
            for (int q = 0; q < 4; ++q)
                o[jf][q] *= cq[q];

        // O += P * V   (P rows = q, Vt[d][kv])
        #pragma unroll
        for (int ks = 0; ks < 2; ++ks) {
            short8 pa = *reinterpret_cast<short8*>(&Ps[(w * 16 + c) * 72 + ks * 32 + g * 8]);
            #pragma unroll
            for (int jf = 0; jf < 4; ++jf) {
                short8 vb = *reinterpret_cast<short8*>(&Vt[(jf * 16 + c) * 72 + ks * 32 + g * 8]);
                o[jf] = __builtin_amdgcn_mfma_f32_16x16x32_bf16(pa, vb, o[jf], 0, 0, 0);
            }
        }
        __syncthreads();
    }

    float lq[4];
    #pragma unroll
    for (int q = 0; q < 4; ++q) lq[q] = 1.f / __shfl(l, g * 4 + q);
    #pragma unroll
    for (int jf = 0; jf < 4; ++jf)
        #pragma unroll
        for (int q = 0; q < 4; ++q) {
            int r = w * 16 + g * 4 + q;
            int d = jf * 16 + c;
            size_t idx = (size_t)r * 512 + d;
            Og[idx] = o[jf][q] * lq[q] + Rg[idx];
        }
}

// ---------------- LayerNorm (one wave per 512-row) ----------------
__global__ __launch_bounds__(64) void k_ln(
    const float* __restrict__ in, float* __restrict__ outF,
    short* __restrict__ outB, const float* __restrict__ gamma,
    const float* __restrict__ beta)
{
    int row = blockIdx.x, lane = threadIdx.x;
    const float* x = in + (size_t)row * 512;
    float4 v0 = *reinterpret_cast<const float4*>(&x[lane * 8]);
    float4 v1 = *reinterpret_cast<const float4*>(&x[lane * 8 + 4]);
    float vals[8] = {v0.x, v0.y, v0.z, v0.w, v1.x, v1.y, v1.z, v1.w};
    float sum = 0.f, sq = 0.f;
    #pragma unroll
    for (int j = 0; j < 8; ++j) { sum += vals[j]; sq += vals[j] * vals[j]; }
    #pragma unroll
    for (int mask = 32; mask; mask >>= 1) {
        sum += __shfl_xor(sum, mask);
        sq  += __shfl_xor(sq, mask);
    }
    float mean = sum * (1.f / 512.f);
    float var  = sq * (1.f / 512.f) - mean * mean;
    float rstd = rsqrtf(var + 1e-5f);
    #pragma unroll
    for (int j = 0; j < 8; ++j) {
        int col = lane * 8 + j;
        float y = (vals[j] - mean) * rstd * gamma[col] + beta[col];
        size_t idx = (size_t)row * 512 + col;
        if (outF) outF[idx] = y;
        if (outB) outB[idx] = f2bf(y);
    }
}

extern "C" void kernel_launch(void* const* d_in, const int* in_sizes, int n_in,
                              void* d_out, int out_size, void* d_ws, size_t ws_size,
                              hipStream_t stream) {
    const float* Q   = (const float*)d_in[0];
    const float* K   = (const float*)d_in[1];
    const float* Wq  = (const float*)d_in[2];
    const float* bq  = (const float*)d_in[3];
    const float* Wk  = (const float*)d_in[4];
    const float* bk  = (const float*)d_in[5];
    const float* Wv  = (const float*)d_in[6];
    const float* bv  = (const float*)d_in[7];
    const float* Wo  = (const float*)d_in[8];
    const float* bo  = (const float*)d_in[9];
    const float* g0  = (const float*)d_in[10];
    const float* be0 = (const float*)d_in[11];
    const float* g1  = (const float*)d_in[12];
    const float* be1 = (const float*)d_in[13];
    float* out = (float*)d_out;
    char* ws = (char*)d_ws;
    const size_t MB = 1024 * 1024;

    short* Qb   = (short*)(ws + 0);
    short* Kb   = (short*)(ws + 8 * MB);
    short* Wqt  = (short*)(ws + 16 * MB);
    short* Wkt  = (short*)(ws + 16 * MB + 512 * 1024);
    short* Wvt  = (short*)(ws + 17 * MB);
    short* Wot  = (short*)(ws + 17 * MB + 512 * 1024);
    float* Qp   = (float*)(ws + 18 * MB);
    short* Qpb  = (short*)(ws + 34 * MB);
    short* Kpb  = (short*)(ws + 42 * MB);
    short* Vpb  = (short*)(ws + 50 * MB);
    float* Oa   = (float*)(ws + 0);        // reuses Qb/Kb
    float* ln0f = (float*)(ws + 42 * MB);  // reuses Kpb/Vpb
    short* ln0b = (short*)(ws + 34 * MB);  // reuses Qpb
    float* out2 = (float*)(ws + 18 * MB);  // reuses Qp

    int n = NBATCH * NQL * DIMV;  // 4194304
    k_f32_to_bf16<<<n / 4 / 256, 256, 0, stream>>>(Q, Qb, n);
    k_f32_to_bf16<<<n / 4 / 256, 256, 0, stream>>>(K, Kb, n);
    dim3 tb(32, 8), tg(16, 16);
    k_transpose_w<<<tg, tb, 0, stream>>>(Wq, Wqt);
    k_transpose_w<<<tg, tb, 0, stream>>>(Wk, Wkt);
    k_transpose_w<<<tg, tb, 0, stream>>>(Wv, Wvt);
    k_transpose_w<<<tg, tb, 0, stream>>>(Wo, Wot);

    dim3 gg(4, 64);  // N/128 x M/128
    k_gemm<0><<<gg, 256, 0, stream>>>(Qb, Wqt, bq, Qp, Qpb, nullptr);
    k_gemm<1><<<gg, 256, 0, stream>>>(Kb, Wkt, bk, nullptr, Kpb, nullptr);
    k_gemm<1><<<gg, 256, 0, stream>>>(Kb, Wvt, bv, nullptr, Vpb, nullptr);

    k_attn<<<NBATCH * NHEAD * (NQL / 64), 256, 0, stream>>>(Qpb, Kpb, Vpb, Qp, Oa);

    k_ln<<<NBATCH * NQL, 64, 0, stream>>>(Oa, ln0f, ln0b, g0, be0);
    k_gemm<2><<<gg, 256, 0, stream>>>(ln0b, Wot, bo, out2, nullptr, ln0f);
    k_ln<<<NBATCH * NQL, 64, 0, stream>>>(out2, out, nullptr, g1, be1);
}

// Round 4
// 171.048 us; speedup vs baseline: 2.8583x; 1.0892x over previous
//
#include <hip/hip_runtime.h>
#include <hip/hip_bf16.h>

typedef __attribute__((ext_vector_type(8))) short short8;
typedef __attribute__((ext_vector_type(4))) short s16x4;
typedef __attribute__((ext_vector_type(4))) float f32x4;

#define DIMV 512
#define NHEAD 8
#define NBATCH 8
#define NQL 1024
#define NKL 1024
// 1/sqrt(512) * log2(e): QK^T comes out pre-scaled in base-2 domain
#define QSCALE (0.04419417382415922f * 1.44269504088896340f)

__device__ __forceinline__ short f2bf(float f) {
    unsigned int u = __float_as_uint(f);
    unsigned int r = (u + 0x7fffu + ((u >> 16) & 1u)) >> 16;
    return (short)r;
}

// ---------------- f32 -> bf16 convert (grid.y selects Q or K) ----------------
__global__ void k_cvt2(const float* __restrict__ a, const float* __restrict__ b,
                       short* __restrict__ oa, short* __restrict__ ob, int n) {
    const float* src = blockIdx.y ? b : a;
    short* dst = blockIdx.y ? ob : oa;
    int i = (blockIdx.x * blockDim.x + threadIdx.x) * 4;
    if (i < n) {
        float4 v = *reinterpret_cast<const float4*>(src + i);
        s16x4 o;
        o[0] = f2bf(v.x); o[1] = f2bf(v.y); o[2] = f2bf(v.z); o[3] = f2bf(v.w);
        *reinterpret_cast<s16x4*>(dst + i) = o;
    }
}

// ---------------- W[k][n] f32 -> Wt[n][k] bf16, 4 weights in one launch ----------------
__global__ void k_transpose_w4(const float* __restrict__ w0, const float* __restrict__ w1,
                               const float* __restrict__ w2, const float* __restrict__ w3,
                               short* __restrict__ t0, short* __restrict__ t1,
                               short* __restrict__ t2, short* __restrict__ t3) {
    __shared__ float tile[32][33];
    const float* W; short* Wt;
    int z = blockIdx.z;
    if (z == 0)      { W = w0; Wt = t0; }
    else if (z == 1) { W = w1; Wt = t1; }
    else if (z == 2) { W = w2; Wt = t2; }
    else             { W = w3; Wt = t3; }
    int tx = threadIdx.x, ty = threadIdx.y;           // 32 x 8
    int n0 = blockIdx.x * 32, k0 = blockIdx.y * 32;
    #pragma unroll
    for (int r = 0; r < 4; ++r)
        tile[ty + r * 8][tx] = W[(size_t)(k0 + ty + r * 8) * DIMV + n0 + tx];
    __syncthreads();
    #pragma unroll
    for (int r = 0; r < 4; ++r)
        Wt[(size_t)(n0 + ty + r * 8) * DIMV + k0 + tx] = f2bf(tile[tx][ty + r * 8]);
}

// ---------------- GEMM: C[M,512] = A[M,512] @ W  (Bt = W^T, [n][k]) ----------------
// MODE 0: outF = acc+bias (f32) and outB = bf16((acc+bias)*QSCALE)   [Q projection]
// MODE 1: outB = bf16(acc+bias)
// MODE 2: outF = resid + relu(acc+bias)
#define GLS 40  // LDS k-stride (32 + 8 pad)
template<int MODE>
__global__ __launch_bounds__(256) void k_gemm(
    const short* __restrict__ A, const short* __restrict__ Bt,
    const float* __restrict__ bias,
    float* __restrict__ outF, short* __restrict__ outB,
    const float* __restrict__ resid)
{
    __shared__ __align__(16) short As[128 * GLS];
    __shared__ __align__(16) short Bs[128 * GLS];
    int tid = threadIdx.x;
    int lane = tid & 63, wid = tid >> 6;
    int wr = wid >> 1, wc = wid & 1;
    int c = lane & 15, g = lane >> 4;
    int m0 = blockIdx.y * 128, n0 = blockIdx.x * 128;

    f32x4 acc[4][4] = {};

    for (int k0 = 0; k0 < 512; k0 += 32) {
        #pragma unroll
        for (int p = 0; p < 2; ++p) {
            int idx = p * 256 + tid;
            int r = idx >> 2, kc = (idx & 3) * 8;
            *reinterpret_cast<short8*>(&As[r * GLS + kc]) =
                *reinterpret_cast<const short8*>(&A[(size_t)(m0 + r) * 512 + k0 + kc]);
            *reinterpret_cast<short8*>(&Bs[r * GLS + kc]) =
                *reinterpret_cast<const short8*>(&Bt[(size_t)(n0 + r) * 512 + k0 + kc]);
        }
        __syncthreads();
        short8 af[4], bfr[4];
        #pragma unroll
        for (int i = 0; i < 4; ++i)
            af[i] = *reinterpret_cast<short8*>(&As[(wr * 64 + i * 16 + c) * GLS + g * 8]);
        #pragma unroll
        for (int j = 0; j < 4; ++j)
            bfr[j] = *reinterpret_cast<short8*>(&Bs[(wc * 64 + j * 16 + c) * GLS + g * 8]);
        #pragma unroll
        for (int i = 0; i < 4; ++i)
            #pragma unroll
            for (int j = 0; j < 4; ++j)
                acc[i][j] = __builtin_amdgcn_mfma_f32_16x16x32_bf16(af[i], bfr[j], acc[i][j], 0, 0, 0);
        __syncthreads();
    }

    #pragma unroll
    for (int i = 0; i < 4; ++i)
        #pragma unroll
        for (int j = 0; j < 4; ++j) {
            int row = m0 + wr * 64 + i * 16 + g * 4;
            int col = n0 + wc * 64 + j * 16 + c;
            float bb = bias[col];
            #pragma unroll
            for (int q = 0; q < 4; ++q) {
                size_t idx = (size_t)(row + q) * 512 + col;
                float v = acc[i][j][q] + bb;
                if (MODE == 0)      { outF[idx] = v; outB[idx] = f2bf(v * QSCALE); }
                else if (MODE == 1) { outB[idx] = f2bf(v); }
                else                { outF[idx] = resid[idx] + fmaxf(v, 0.f); }
            }
        }
}

// ---------------- fused flash attention with residual ----------------
// Qb is pre-scaled by QSCALE -> softmax runs in base-2 (exp2) domain.
__global__ __launch_bounds__(256) void k_attn(
    const short* __restrict__ Qb, const short* __restrict__ Kb,
    const short* __restrict__ Vb, const float* __restrict__ Resid,
    float* __restrict__ Out)
{
    __shared__ __align__(16) short Qs[64 * 72];
    __shared__ __align__(16) short Ks[64 * 72];
    __shared__ __align__(16) short Vt[64 * 72];
    __shared__ __align__(16) short Ps[64 * 72];
    int tid = threadIdx.x;
    int lane = tid & 63, w = tid >> 6;
    int c = lane & 15, g = lane >> 4;
    int bid = blockIdx.x;
    int qb = bid & 15, h = (bid >> 4) & 7, b = bid >> 7;
    const short* Qg = Qb + (size_t)(b * NQL + qb * 64) * 512 + h * 64;
    const short* Kg = Kb + (size_t)b * NKL * 512 + h * 64;
    const short* Vg = Vb + (size_t)b * NKL * 512 + h * 64;
    const float* Rg = Resid + (size_t)(b * NQL + qb * 64) * 512 + h * 64;
    float* Og = Out + (size_t)(b * NQL + qb * 64) * 512 + h * 64;

    #pragma unroll
    for (int p = 0; p < 2; ++p) {
        int idx = p * 256 + tid;
        int r = idx >> 3, d0 = (idx & 7) * 8;
        *reinterpret_cast<short8*>(&Qs[r * 72 + d0]) =
            *reinterpret_cast<const short8*>(&Qg[(size_t)r * 512 + d0]);
    }

    // stage tile 0: global -> regs -> LDS
    short8 kreg[2], vreg[2];
    int kr[2], kd[2];
    int kv = tid & 63;
    #pragma unroll
    for (int p = 0; p < 2; ++p) {
        int idx = p * 256 + tid;
        kr[p] = idx >> 3; kd[p] = (idx & 7) * 8;
        kreg[p] = *reinterpret_cast<const short8*>(&Kg[(size_t)kr[p] * 512 + kd[p]]);
    }
    #pragma unroll
    for (int p = 0; p < 2; ++p) {
        int d0 = ((tid >> 6) + p * 4) * 8;
        vreg[p] = *reinterpret_cast<const short8*>(&Vg[(size_t)kv * 512 + d0]);
    }
    #pragma unroll
    for (int p = 0; p < 2; ++p)
        *reinterpret_cast<short8*>(&Ks[kr[p] * 72 + kd[p]]) = kreg[p];
    #pragma unroll
    for (int p = 0; p < 2; ++p) {
        int d0 = ((tid >> 6) + p * 4) * 8;
        #pragma unroll
        for (int j = 0; j < 8; ++j) Vt[(d0 + j) * 72 + kv] = vreg[p][j];
    }
    __syncthreads();

    float m = -1e30f, l = 0.f;
    f32x4 o[4] = {};

    for (int t = 0; t < 16; ++t) {
        // async-STAGE: issue next tile's global loads now, write LDS after barrier
        if (t < 15) {
            const short* Kn = Kg + (size_t)(t + 1) * 64 * 512;
            const short* Vn = Vg + (size_t)(t + 1) * 64 * 512;
            #pragma unroll
            for (int p = 0; p < 2; ++p)
                kreg[p] = *reinterpret_cast<const short8*>(&Kn[(size_t)kr[p] * 512 + kd[p]]);
            #pragma unroll
            for (int p = 0; p < 2; ++p) {
                int d0 = ((tid >> 6) + p * 4) * 8;
                vreg[p] = *reinterpret_cast<const short8*>(&Vn[(size_t)kv * 512 + d0]);
            }
        }

        // S^T = K * Q^T (pre-scaled, base-2 domain)
        f32x4 s[4] = {};
        #pragma unroll
        for (int ks = 0; ks < 2; ++ks) {
            short8 bq = *reinterpret_cast<short8*>(&Qs[(w * 16 + c) * 72 + ks * 32 + g * 8]);
            #pragma unroll
            for (int i = 0; i < 4; ++i) {
                short8 ak = *reinterpret_cast<short8*>(&Ks[(i * 16 + c) * 72 + ks * 32 + g * 8]);
                s[i] = __builtin_amdgcn_mfma_f32_16x16x32_bf16(ak, bq, s[i], 0, 0, 0);
            }
        }

        // online softmax, defer-max (THR=8 in log2 domain)
        float r0 = fmaxf(fmaxf(s[0][0], s[0][1]), fmaxf(s[0][2], s[0][3]));
        float r1 = fmaxf(fmaxf(s[1][0], s[1][1]), fmaxf(s[1][2], s[1][3]));
        float r2 = fmaxf(fmaxf(s[2][0], s[2][1]), fmaxf(s[2][2], s[2][3]));
        float r3 = fmaxf(fmaxf(s[3][0], s[3][1]), fmaxf(s[3][2], s[3][3]));
        float rowm = fmaxf(fmaxf(r0, r1), fmaxf(r2, r3));
        rowm = fmaxf(rowm, __shfl_xor(rowm, 16));
        rowm = fmaxf(rowm, __shfl_xor(rowm, 32));
        if (!__all(rowm <= m + 8.f)) {
            float mnew = fmaxf(m, rowm);
            float corr = __builtin_amdgcn_exp2f(m - mnew);
            l *= corr;
            float cq[4];
            #pragma unroll
            for (int q = 0; q < 4; ++q) cq[q] = __shfl(corr, g * 4 + q);
            #pragma unroll
            for (int jf = 0; jf < 4; ++jf)
                #pragma unroll
                for (int q = 0; q < 4; ++q)
                    o[jf][q] *= cq[q];
            m = mnew;
        }
        float psum = 0.f;
        #pragma unroll
        for (int i = 0; i < 4; ++i) {
            s16x4 pk;
            #pragma unroll
            for (int q = 0; q < 4; ++q) {
                float p = __builtin_amdgcn_exp2f(s[i][q] - m);
                psum += p;
                pk[q] = f2bf(p);
            }
            *reinterpret_cast<s16x4*>(&Ps[(w * 16 + c) * 72 + i * 16 + g * 4]) = pk;
        }
        psum += __shfl_xor(psum, 16);
        psum += __shfl_xor(psum, 32);
        l += psum;

        // O += P * V   (P rows = q, Vt[d][kv])
        #pragma unroll
        for (int ks = 0; ks < 2; ++ks) {
            short8 pa = *reinterpret_cast<short8*>(&Ps[(w * 16 + c) * 72 + ks * 32 + g * 8]);
            #pragma unroll
            for (int jf = 0; jf < 4; ++jf) {
                short8 vb = *reinterpret_cast<short8*>(&Vt[(jf * 16 + c) * 72 + ks * 32 + g * 8]);
                o[jf] = __builtin_amdgcn_mfma_f32_16x16x32_bf16(pa, vb, o[jf], 0, 0, 0);
            }
        }

        if (t < 15) {
            __syncthreads();   // all waves done reading Ks/Vt
            #pragma unroll
            for (int p = 0; p < 2; ++p)
                *reinterpret_cast<short8*>(&Ks[kr[p] * 72 + kd[p]]) = kreg[p];
            #pragma unroll
            for (int p = 0; p < 2; ++p) {
                int d0 = ((tid >> 6) + p * 4) * 8;
                #pragma unroll
                for (int j = 0; j < 8; ++j) Vt[(d0 + j) * 72 + kv] = vreg[p][j];
            }
            __syncthreads();   // next tile visible
        }
    }

    float linv = 1.f / l;
    float lq[4];
    #pragma unroll
    for (int q = 0; q < 4; ++q) lq[q] = __shfl(linv, g * 4 + q);
    #pragma unroll
    for (int jf = 0; jf < 4; ++jf)
        #pragma unroll
        for (int q = 0; q < 4; ++q) {
            int r = w * 16 + g * 4 + q;
            int d = jf * 16 + c;
            size_t idx = (size_t)r * 512 + d;
            Og[idx] = o[jf][q] * lq[q] + Rg[idx];
        }
}

// ---------------- LayerNorm (one wave per 512-row) ----------------
__global__ __launch_bounds__(64) void k_ln(
    const float* __restrict__ in, float* __restrict__ outF,
    short* __restrict__ outB, const float* __restrict__ gamma,
    const float* __restrict__ beta)
{
    int row = blockIdx.x, lane = threadIdx.x;
    const float* x = in + (size_t)row * 512;
    float4 v0 = *reinterpret_cast<const float4*>(&x[lane * 8]);
    float4 v1 = *reinterpret_cast<const float4*>(&x[lane * 8 + 4]);
    float vals[8] = {v0.x, v0.y, v0.z, v0.w, v1.x, v1.y, v1.z, v1.w};
    float sum = 0.f, sq = 0.f;
    #pragma unroll
    for (int j = 0; j < 8; ++j) { sum += vals[j]; sq += vals[j] * vals[j]; }
    #pragma unroll
    for (int mask = 32; mask; mask >>= 1) {
        sum += __shfl_xor(sum, mask);
        sq  += __shfl_xor(sq, mask);
    }
    float mean = sum * (1.f / 512.f);
    float var  = sq * (1.f / 512.f) - mean * mean;
    float rstd = rsqrtf(var + 1e-5f);
    #pragma unroll
    for (int j = 0; j < 8; ++j) {
        int col = lane * 8 + j;
        float y = (vals[j] - mean) * rstd * gamma[col] + beta[col];
        size_t idx = (size_t)row * 512 + col;
        if (outF) outF[idx] = y;
        if (outB) outB[idx] = f2bf(y);
    }
}

extern "C" void kernel_launch(void* const* d_in, const int* in_sizes, int n_in,
                              void* d_out, int out_size, void* d_ws, size_t ws_size,
                              hipStream_t stream) {
    const float* Q   = (const float*)d_in[0];
    const float* K   = (const float*)d_in[1];
    const float* Wq  = (const float*)d_in[2];
    const float* bq  = (const float*)d_in[3];
    const float* Wk  = (const float*)d_in[4];
    const float* bk  = (const float*)d_in[5];
    const float* Wv  = (const float*)d_in[6];
    const float* bv  = (const float*)d_in[7];
    const float* Wo  = (const float*)d_in[8];
    const float* bo  = (const float*)d_in[9];
    const float* g0  = (const float*)d_in[10];
    const float* be0 = (const float*)d_in[11];
    const float* g1  = (const float*)d_in[12];
    const float* be1 = (const float*)d_in[13];
    float* out = (float*)d_out;
    char* ws = (char*)d_ws;
    const size_t MB = 1024 * 1024;

    short* Qb   = (short*)(ws + 0);
    short* Kb   = (short*)(ws + 8 * MB);
    short* Wqt  = (short*)(ws + 16 * MB);
    short* Wkt  = (short*)(ws + 16 * MB + 512 * 1024);
    short* Wvt  = (short*)(ws + 17 * MB);
    short* Wot  = (short*)(ws + 17 * MB + 512 * 1024);
    float* Qp   = (float*)(ws + 18 * MB);
    short* Qpb  = (short*)(ws + 34 * MB);
    short* Kpb  = (short*)(ws + 42 * MB);
    short* Vpb  = (short*)(ws + 50 * MB);
    float* Oa   = (float*)(ws + 0);        // reuses Qb/Kb
    float* ln0f = (float*)(ws + 42 * MB);  // reuses Kpb/Vpb
    short* ln0b = (short*)(ws + 34 * MB);  // reuses Qpb
    float* out2 = (float*)(ws + 18 * MB);  // reuses Qp

    int n = NBATCH * NQL * DIMV;  // 4194304
    dim3 cg(n / 4 / 256, 2);
    k_cvt2<<<cg, 256, 0, stream>>>(Q, K, Qb, Kb, n);
    dim3 tb(32, 8), tg(16, 16, 4);
    k_transpose_w4<<<tg, tb, 0, stream>>>(Wq, Wk, Wv, Wo, Wqt, Wkt, Wvt, Wot);

    dim3 gg(4, 64);  // N/128 x M/128
    k_gemm<0><<<gg, 256, 0, stream>>>(Qb, Wqt, bq, Qp, Qpb, nullptr);
    k_gemm<1><<<gg, 256, 0, stream>>>(Kb, Wkt, bk, nullptr, Kpb, nullptr);
    k_gemm<1><<<gg, 256, 0, stream>>>(Kb, Wvt, bv, nullptr, Vpb, nullptr);

    k_attn<<<NBATCH * NHEAD * (NQL / 64), 256, 0, stream>>>(Qpb, Kpb, Vpb, Qp, Oa);

    k_ln<<<NBATCH * NQL, 64, 0, stream>>>(Oa, ln0f, ln0b, g0, be0);
    k_gemm<2><<<gg, 256, 0, stream>>>(ln0b, Wot, bo, out2, nullptr, ln0f);
    k_ln<<<NBATCH * NQL, 64, 0, stream>>>(out2, out, nullptr, g1, be1);
}